// Round 8
// baseline (2112.546 us; speedup 1.0000x reference)
//
#include <hip/hip_runtime.h>

// PadeKANLayer: B=4096, IN=256, OUT=256, 8 spline terms, UNIFORM grid (h=0.4).
// R18 = R17 + unroll-by-2 double-register-set pipeline.
// R17 lesson: 1-deep prefetch recovered latency (VALUBusy 64->75%, 128->110us)
// but compiler kept VGPR=48 => rotation movs (~20/iter) still in stream and
// late loads under-covered. R18: two NAMED register sets A/B alternate
// (no rotation), 4 seg x 4 pairs; each set's loads issue one full glue body
// (~300+ cyc) before use. Final A-prefetch over-reads exactly 1 iter (i=32),
// verified to land inside the workspace for all 5 streams; never consumed.
// Tier-2 fallback: R11 kernel. Tier-3: scalar fallback.

#define IN_F 256
#define OUT_F 256
#define B_TOTAL 4096
#define NWAVE 4
#define NS 4

constexpr float L2E = 1.4426950408889634f;   // log2(e)
constexpr float LN2 = 0.6931471805599453f;   // ln(2)

typedef _Float16 f16x8 __attribute__((ext_vector_type(8)));
typedef float    f32x16 __attribute__((ext_vector_type(16)));

__device__ __forceinline__ float fast_exp2(float a) { return __builtin_amdgcn_exp2f(a); }
__device__ __forceinline__ float fast_log2(float a) { return __builtin_amdgcn_logf(a); }
__device__ __forceinline__ float fast_rcp(float a)  { return __builtin_amdgcn_rcpf(a); }

// ======================= TIER 1: MFMA v7 =======================

// prep5 sections (unchanged):
//  [0,1024)    x 64x16 tiles: transpose -> sbpk (f16x8), ex, siluH/L
//  [1024,1280) weight pack: bfN/bfD (den side *L2E), misc2, bwp
//  [1280,1536) row stats l2s/prs
//  [1536,2560) zero out[]
__global__ __launch_bounds__(256)
void prep5(const float* __restrict__ bw, const float* __restrict__ nw,
           const float* __restrict__ dw, const float* __restrict__ hb,
           const float* __restrict__ hw, const float* __restrict__ lw,
           const float* __restrict__ pw, const float* __restrict__ x,
           f16x8* __restrict__ sbpk, float* __restrict__ ex,
           _Float16* __restrict__ silu2,       // [2][B][IN]  (H, L)
           _Float16* __restrict__ bwp,          // [OUT][IN]
           f16x8* __restrict__ bfN, f16x8* __restrict__ bfD,
           float2* __restrict__ misc2,          // [IN][OUT]
           float* __restrict__ l2s, float* __restrict__ prs,
           float* __restrict__ out, int out_n)
{
    if (blockIdx.x < 1024) {
        // spline/ex/silu: block = 64 b x 16 i tile
        __shared__ float xs[64][17];
        __shared__ __align__(16) _Float16 sil[2][64][16];
        const int bt = blockIdx.x >> 4;   // 0..63
        const int it = blockIdx.x & 15;   // 0..15
        const int b0 = bt * 64;
        const int i0 = it * 16;
        {
            const int rr = threadIdx.x >> 2;          // 0..63 (b)
            const int c4 = (threadIdx.x & 3) * 4;     // 0,4,8,12 (i)
            const float4 v = *reinterpret_cast<const float4*>(
                x + (size_t)(b0 + rr) * IN_F + i0 + c4);
            xs[rr][c4] = v.x; xs[rr][c4 + 1] = v.y;
            xs[rr][c4 + 2] = v.z; xs[rr][c4 + 3] = v.w;
        }
        __syncthreads();
        const int bl = threadIdx.x & 63;
        const int ig = threadIdx.x >> 6;              // 0..3
        #pragma unroll
        for (int k = 0; k < 4; ++k) {
            const int il = ig * 4 + k;
            const int i = i0 + il;
            const float xv = xs[bl][il];
            // e_x (clamped so q = 1+e_hb*e_x stays finite)
            ex[(size_t)i * B_TOTAL + b0 + bl] =
                fast_exp2(fminf(-50.0f * L2E * xv, 58.0f));
            // silu hi/lo f16 split (for base MFMA)
            const float sl = xv * fast_rcp(1.0f + fast_exp2(-L2E * xv));
            const _Float16 sH = (_Float16)sl;
            sil[0][bl][il] = sH;
            sil[1][bl][il] = (_Float16)(sl - (float)sH);
            // closed-form uniform cubic B-spline; g0=-2.2, h=0.4 (build_grid)
            const float tt = (xv + 2.2f) * 2.5f;
            const float sf = floorf(tt);
            const float u  = tt - sf;
            const float u2 = u * u;
            const float u3 = u2 * u;
            const float om = 1.0f - u;
            const float W0 = om * om * om * (1.0f / 6.0f);
            const float W1 = fmaf(3.0f, u3, fmaf(-6.0f, u2, 4.0f)) * (1.0f / 6.0f);
            const float W2 = fmaf(-3.0f, u3, fmaf(3.0f, u2, fmaf(3.0f, u, 1.0f))) * (1.0f / 6.0f);
            const float W3 = u3 * (1.0f / 6.0f);
            const int  siq = (int)sf;
            f16x8 sb8;
            #pragma unroll
            for (int j = 0; j < 8; ++j) {
                float v = 0.f;
                v = (siq == j + 3) ? W0 : v;
                v = (siq == j + 2) ? W1 : v;
                v = (siq == j + 1) ? W2 : v;
                v = (siq == j    ) ? W3 : v;
                sb8[j] = (_Float16)v;
            }
            sbpk[(size_t)i * B_TOTAL + b0 + bl] = sb8;
        }
        __syncthreads();
        {
            // coalesced silu2 writeout: [2][B][IN] f16, 16B per thread
            const int hl = threadIdx.x >> 7;          // 0..1
            const int b2 = (threadIdx.x >> 1) & 63;   // 0..63
            const int ch = threadIdx.x & 1;           // 0..1
            const f16x8 v = *reinterpret_cast<const f16x8*>(&sil[hl][b2][ch * 8]);
            *reinterpret_cast<f16x8*>(
                silu2 + (size_t)hl * B_TOTAL * IN_F +
                (size_t)(b0 + b2) * IN_F + i0 + ch * 8) = v;
        }
    } else if (blockIdx.x < 1280) {
        // weight pack: block = i, thread = o. Den side pre-scaled by L2E.
        const int i = blockIdx.x - 1024;
        const int o = threadIdx.x;
        const int oi = o * IN_F + i;
        const float* n8 = nw + (size_t)oi * 8;
        const float* d8 = dw + (size_t)oi * 8;
        f16x8 vhi, vlo, vd;
        #pragma unroll
        for (int k = 0; k < 8; ++k) {
            const float nv = n8[k];
            const _Float16 h = (_Float16)nv;
            vhi[k] = h;
            vlo[k] = (_Float16)(nv - (float)h);
            vd[k]  = (_Float16)(d8[k] * L2E);
        }
        const float lwv = lw[oi] * L2E, pwv = pw[oi] * L2E;
        const _Float16 lwh = (_Float16)lwv;
        const _Float16 lwl = (_Float16)(lwv - (float)lwh);
        const _Float16 cEh = (_Float16)L2E;
        const _Float16 cEl = (_Float16)(L2E - (float)cEh);
        const _Float16 z0 = (_Float16)0.0f;
        // stats B half (k=8..15): pairs with A stat8 {l2h,l2h,l2l,prs,1,1,0,0}
        const f16x8 vs = {lwh, lwl, lwh, (_Float16)pwv, cEh, cEl, z0, z0};
        const int ot = o >> 5, ol = o & 31;
        const size_t base = ((size_t)i * 8 + ot) * 64;
        bfN[base + ol]      = vhi;   // lanes 0-31: k=0..7  (sb x wn_hi)
        bfN[base + 32 + ol] = vlo;   // lanes 32-63: k=8..15 (sb x wn_lo)
        bfD[base + ol]      = vd;    // k=0..7 (sb x wd*L2E)
        bfD[base + 32 + ol] = vs;    // k=8..13 stats weights (*L2E)
        misc2[(size_t)i * OUT_F + o] =
            make_float2(fast_exp2(hb[oi] * (50.0f * L2E)), hw[oi]);
        bwp[(size_t)o * IN_F + i] = (_Float16)bw[oi];
    } else if (blockIdx.x < 1536) {
        // row stats: 256 blocks x 4 waves, each wave reduces 4 rows
        const int blk = blockIdx.x - 1280;
        const int wv = threadIdx.x >> 6;
        const int lane = threadIdx.x & 63;
        const int row = blk * NWAVE + wv;
        #pragma unroll
        for (int rr = 0; rr < 4; ++rr) {
            const int r = row * 4 + rr;               // 0..4095
            const float* xr = x + (size_t)r * IN_F;
            float pl2 = 0.f, ppr = 1.f;
            #pragma unroll
            for (int c = 0; c < 4; ++c) {
                float xv = xr[c * 64 + lane];
                pl2 = fmaf(xv, xv, pl2);
                ppr *= xv;
            }
            #pragma unroll
            for (int m = 1; m < 64; m <<= 1) {
                pl2 += __shfl_xor(pl2, m);
                ppr *= __shfl_xor(ppr, m);
            }
            if (lane == 0) { l2s[r] = pl2; prs[r] = ppr; }
        }
    } else {
        const size_t base = ((size_t)(blockIdx.x - 1536) * 256 + threadIdx.x) * 4;
        if (base + 4 <= (size_t)out_n)
            *reinterpret_cast<float4*>(out + base) = make_float4(0.f, 0.f, 0.f, 0.f);
    }
}

// main: 2048 blocks = 8 xcd x (8 ot x 16 btl x 2 ih). Unroll-2 double-set
// software pipeline: sets A/B alternate, no rotation movs.
// C layout (verified 32x32): col = lane&31 (=o), row = (r&3)+8*(r>>2)+4*(lane>>5).
__global__ __launch_bounds__(256, 4)
void padekan_mfma7(const f16x8* __restrict__ sbpk, const float* __restrict__ ex,
                   const _Float16* __restrict__ silu2, const _Float16* __restrict__ bwp,
                   const f16x8* __restrict__ bfN, const f16x8* __restrict__ bfD,
                   const float2* __restrict__ misc2, const float* __restrict__ l2s,
                   const float* __restrict__ prs, float* __restrict__ out)
{
    __shared__ float red[NS][64][17];   // 17408 B

    const int lane = threadIdx.x & 63;
    const int wv = threadIdx.x >> 6;    // i-chunk
    const int xcd = blockIdx.x & 7;     // XCD -> b-tile group
    const int r   = blockIdx.x >> 3;    // 0..255
    const int ot  = r >> 5;             // 0..7  (slow per XCD: weights swap)
    const int btl = (r >> 1) & 15;      // 0..15
    const int ih  = r & 1;              // i-half
    const int bt  = xcd * 16 + btl;     // 0..127
    const int bl = lane & 31;
    const int hi = lane >> 5;
    const int b0 = bt * 32;
    const int bme = b0 + bl;

    // stats A half (hi lanes, k=8..15): {l2hi,l2hi,l2lo,prs,1,1,0,0}
    const float l2v = l2s[bme];
    const float prv = prs[bme];
    const _Float16 l2h = (_Float16)l2v;
    const _Float16 l2l = (_Float16)(l2v - (float)l2h);
    const _Float16 z0 = (_Float16)0.0f;
    const _Float16 one = (_Float16)1.0f;
    const f16x8 stat8 = {l2h, l2h, l2l, (_Float16)prv, one, one, z0, z0};

    const f32x16 zero16 = {};
    f32x16 acc = {};

    const int i0 = ih * 128 + wv * 32;

    const f16x8*    sb_p = sbpk + (size_t)i0 * B_TOTAL + bme;
    const f16x8*    bn_p = bfN + ((size_t)i0 * 8 + ot) * 64 + lane;
    const f16x8*    bd_p = bfD + ((size_t)i0 * 8 + ot) * 64 + lane;
    const float2*   mi_p = misc2 + (size_t)i0 * OUT_F + ot * 32 + bl;
    const float*    ep   = ex + (size_t)i0 * B_TOTAL + b0 + hi * 4;
    const _Float16* si_p = silu2 + (size_t)hi * (B_TOTAL * IN_F) + (size_t)bme * IN_F + i0;
    const _Float16* bw_p = bwp + (size_t)(ot * 32 + bl) * IN_F + i0;

    // two named register sets (no rotation movs)
    f16x8 sbvA, vbNA, vbDA, sbvB, vbNB, vbDB;
    float2 miA, miB;
    float4 e0A, e1A, e2A, e3A, e0B, e1B, e2B, e3B;

#define LOADSET(S)                                               \
    sbv##S = *sb_p; vbN##S = *bn_p; vbD##S = *bd_p; mi##S = *mi_p; \
    e0##S = *reinterpret_cast<const float4*>(ep);                 \
    e1##S = *reinterpret_cast<const float4*>(ep + 8);             \
    e2##S = *reinterpret_cast<const float4*>(ep + 16);            \
    e3##S = *reinterpret_cast<const float4*>(ep + 24);            \
    sb_p += B_TOTAL; bn_p += 8 * 64; bd_p += 8 * 64;              \
    mi_p += OUT_F; ep += B_TOTAL;

    // one MFMA pair + 16-element glue on the given register set
    auto glue = [&](const f16x8& sbv_c, const f16x8& vbN_c, const f16x8& vbD_c,
                    const float2& mi_c, const float4& eA0, const float4& eA1,
                    const float4& eA2, const float4& eA3) {
        const f16x8 aD = hi ? stat8 : sbv_c;
        f32x16 cn = __builtin_amdgcn_mfma_f32_32x32x16_f16(sbv_c, vbN_c, zero16, 0, 0, 0);
        f32x16 cd = __builtin_amdgcn_mfma_f32_32x32x16_f16(aD, vbD_c, zero16, 0, 0, 0);
        const float4 eAs[4] = {eA0, eA1, eA2, eA3};
        #pragma unroll
        for (int gq = 0; gq < 4; ++gq) {
            const float exq[4] = {eAs[gq].x, eAs[gq].y, eAs[gq].z, eAs[gq].w};
            #pragma unroll
            for (int j = 0; j < 4; ++j) {
                const int rr_ = gq * 4 + j;
                // cd = L2E*den (pre-scaled); naive softplus exact for |den|<85
                const float t1  = fast_exp2(cd[rr_]);
                const float spe = fmaf(fast_log2(1.0f + t1), LN2, 1e-4f);
                const float q   = fmaf(exq[j], mi_c.x, 1.0f);
                const float rrv = fast_rcp(q * spe);
                acc[rr_] = fmaf(fmaf(cn[rr_], q, mi_c.y), rrv, acc[rr_]);
            }
        }
    };

    LOADSET(A)                         // preload i = 0

    #pragma unroll 1
    for (int seg = 0; seg < 4; ++seg) {
        // base_out MFMA: k0-7 = silu_hi x bw, k8-15 = silu_lo x bw (8 i's)
        {
            const f16x8 sfr = *reinterpret_cast<const f16x8*>(si_p);
            const f16x8 wfr = *reinterpret_cast<const f16x8*>(bw_p);
            si_p += 8; bw_p += 8;
            acc = __builtin_amdgcn_mfma_f32_32x32x16_f16(sfr, wfr, acc, 0, 0, 0);
        }
        #pragma unroll
        for (int p = 0; p < 4; ++p) {
            LOADSET(B)                 // prefetch odd iter
            glue(sbvA, vbNA, vbDA, miA, e0A, e1A, e2A, e3A);
            LOADSET(A)                 // prefetch next even iter
            // (final LOADSET(A) over-reads i=32 by design: all 5 streams
            //  land in adjacent workspace regions; values never consumed)
            glue(sbvB, vbNB, vbDB, miB, e0B, e1B, e2B, e3B);
        }
    }
#undef LOADSET

    // cross-wave reduce (4 i-chunks), atomic combine of the 2 ih halves
    #pragma unroll
    for (int oo = 0; oo < 16; ++oo) red[wv][lane][oo] = acc[oo];
    __syncthreads();
    #pragma unroll
    for (int e = 0; e < 4; ++e) {
        const int l = threadIdx.x & 63;
        const int rr_ = (threadIdx.x >> 6) + e * 4;     // 0..15
        const float s = (red[0][l][rr_] + red[1][l][rr_]) +
                        (red[2][l][rr_] + red[3][l][rr_]);
        const int row = (rr_ & 3) + 8 * (rr_ >> 2) + 4 * (l >> 5);
        atomicAdd(&out[(size_t)(b0 + row) * OUT_F + ot * 32 + (l & 31)], s);
    }
}

// ======================= TIER 2: R11 MFMA path =======================

__global__ __launch_bounds__(256)
void prep_mfma(const float* __restrict__ bw, const float* __restrict__ nw,
               const float* __restrict__ dw, const float* __restrict__ hb,
               const float* __restrict__ hw, const float* __restrict__ lw,
               const float* __restrict__ pw, const float* __restrict__ x,
               float* __restrict__ xT, float2* __restrict__ exsi,
               f16x8* __restrict__ bfN, f16x8* __restrict__ bfD,
               float4* __restrict__ misc,
               float* __restrict__ l2s, float* __restrict__ prs)
{
    if (blockIdx.x < 256) {
        const int i = blockIdx.x;
        const int o = threadIdx.x;
        const int oi = o * IN_F + i;
        const float* n8 = nw + (size_t)oi * 8;
        const float* d8 = dw + (size_t)oi * 8;
        f16x8 vhi, vlo, vd;
        #pragma unroll
        for (int k = 0; k < 8; ++k) {
            const float nv = n8[k];
            const _Float16 h = (_Float16)nv;
            vhi[k] = h;
            vlo[k] = (_Float16)(nv - (float)h);
            vd[k]  = (_Float16)d8[k];
        }
        const float lwv = lw[oi], pwv = pw[oi];
        const _Float16 lwh = (_Float16)lwv;
        const _Float16 lwl = (_Float16)(lwv - (float)lwh);
        const _Float16 z0 = (_Float16)0.0f;
        const f16x8 vs = {lwh, lwl, lwh, (_Float16)pwv, (_Float16)1.0f, z0, z0, z0};
        const int ot = o >> 5, ol = o & 31;
        const size_t base = ((size_t)i * 8 + ot) * 64;
        bfN[base + ol]      = vhi;
        bfN[base + 32 + ol] = vlo;
        bfD[base + ol]      = vd;
        bfD[base + 32 + ol] = vs;
        misc[(size_t)i * OUT_F + o] =
            make_float4(fast_exp2(hb[oi] * (50.0f * L2E)), hw[oi], bw[oi], 0.0f);
    } else if (blockIdx.x < 512) {
        __shared__ float t[64][65];
        const int blk = blockIdx.x - 256;
        const int bt = blk >> 2;
        const int it = blk & 3;
        const int c  = threadIdx.x & 63;
        const int r0 = threadIdx.x >> 6;
        #pragma unroll
        for (int rr = 0; rr < 16; ++rr) {
            const int r = r0 * 16 + rr;
            t[r][c] = x[(size_t)(bt * 64 + r) * IN_F + it * 64 + c];
        }
        __syncthreads();
        #pragma unroll
        for (int rr = 0; rr < 16; ++rr) {
            const int r = r0 * 16 + rr;
            const float v = t[c][r];
            const size_t idx = (size_t)(it * 64 + r) * B_TOTAL + bt * 64 + c;
            xT[idx] = v;
            const float exv = fast_exp2(fminf(-50.0f * L2E * v, 58.0f));
            const float sl = v * fast_rcp(1.0f + fast_exp2(-L2E * v));
            exsi[idx] = make_float2(exv, sl);
        }
    } else {
        const int blk = blockIdx.x - 512;
        const int wv = threadIdx.x >> 6;
        const int lane = threadIdx.x & 63;
        const int row = blk * NWAVE + wv;
        #pragma unroll
        for (int rr = 0; rr < 4; ++rr) {
            const int r = row * 4 + rr;
            const float* xr = x + (size_t)r * IN_F;
            float pl2 = 0.f, ppr = 1.f;
            #pragma unroll
            for (int c = 0; c < 4; ++c) {
                float xv = xr[c * 64 + lane];
                pl2 = fmaf(xv, xv, pl2);
                ppr *= xv;
            }
            #pragma unroll
            for (int m = 1; m < 64; m <<= 1) {
                pl2 += __shfl_xor(pl2, m);
                ppr *= __shfl_xor(ppr, m);
            }
            if (lane == 0) { l2s[r] = pl2; prs[r] = ppr; }
        }
    }
}

__global__ __launch_bounds__(256, 4)
void padekan_mfma(const float* __restrict__ xT, const float2* __restrict__ exsi,
                  const f16x8* __restrict__ bfN, const f16x8* __restrict__ bfD,
                  const float4* __restrict__ misc, const float* __restrict__ l2s,
                  const float* __restrict__ prs, const float* __restrict__ grid,
                  float* __restrict__ out)
{
    __shared__ float red[NS][64][17];

    const int lane = threadIdx.x & 63;
    const int wv = threadIdx.x >> 6;
    const int ot = blockIdx.x & 7;
    const int bt = blockIdx.x >> 3;
    const int bl = lane & 31;
    const int hi = lane >> 5;
    const int b0 = bt * 32;

    const float g0 = grid[0];
    const float inv_h = 1.0f / (grid[1] - grid[0]);

    const float l2v = l2s[b0 + bl];
    const float prv = prs[b0 + bl];
    const _Float16 l2h = (_Float16)l2v;
    const _Float16 l2l = (_Float16)(l2v - (float)l2h);
    const _Float16 z0 = (_Float16)0.0f;
    const f16x8 stat8 = {l2h, l2h, l2l, (_Float16)prv, (_Float16)1.0f, z0, z0, z0};

    const f32x16 zero16 = {};
    f32x16 acc = {};

    const int i0 = wv * 64;
    #pragma unroll 1
    for (int ii = 0; ii < 64; ++ii) {
        const int i = i0 + ii;
        const float xv = xT[(size_t)i * B_TOTAL + b0 + bl];

        const float t  = (xv - g0) * inv_h;
        const float sf = floorf(t);
        const float u  = t - sf;
        const float u2 = u * u;
        const float u3 = u2 * u;
        const float om = 1.0f - u;
        const float W0 = om * om * om * (1.0f / 6.0f);
        const float W1 = fmaf(3.0f, u3, fmaf(-6.0f, u2, 4.0f)) * (1.0f / 6.0f);
        const float W2 = fmaf(-3.0f, u3, fmaf(3.0f, u2, fmaf(3.0f, u, 1.0f))) * (1.0f / 6.0f);
        const float W3 = u3 * (1.0f / 6.0f);
        const int  si = (int)sf;

        f16x8 aN;
        #pragma unroll
        for (int j = 0; j < 8; ++j) {
            float v = 0.f;
            v = (si == j + 3) ? W0 : v;
            v = (si == j + 2) ? W1 : v;
            v = (si == j + 1) ? W2 : v;
            v = (si == j    ) ? W3 : v;
            aN[j] = (_Float16)v;
        }
        const f16x8 aD = hi ? stat8 : aN;

        const size_t fb = ((size_t)i * 8 + ot) * 64 + lane;
        const f16x8 vbN = bfN[fb];
        const f16x8 vbD = bfD[fb];
        const float4 mi = misc[(size_t)i * OUT_F + ot * 32 + bl];

        f32x16 cn = __builtin_amdgcn_mfma_f32_32x32x16_f16(aN, vbN, zero16, 0, 0, 0);
        f32x16 cd = __builtin_amdgcn_mfma_f32_32x32x16_f16(aD, vbD, zero16, 0, 0, 0);

        const float2* ep = exsi + (size_t)i * B_TOTAL + b0 + hi * 4;
        #pragma unroll
        for (int gq = 0; gq < 4; ++gq) {
            const float4 eA = *reinterpret_cast<const float4*>(ep + gq * 8);
            const float4 eB = *reinterpret_cast<const float4*>(ep + gq * 8 + 2);
            const float exq[4] = {eA.x, eA.z, eB.x, eB.z};
            const float svq[4] = {eA.y, eA.w, eB.y, eB.w};
            #pragma unroll
            for (int j = 0; j < 4; ++j) {
                const int r = gq * 4 + j;
                const float den = cd[r];
                const float ttv = fast_exp2(-L2E * fabsf(den));
                const float sp  = fmaf(fast_log2(1.0f + ttv), LN2, fmaxf(den, 0.0f));
                const float q   = fmaf(exq[j], mi.x, 1.0f);
                const float rrv = fast_rcp(q * (sp + 1e-4f));
                const float numer = fmaf(cn[r], q, mi.y);
                acc[r] = fmaf(svq[j], mi.z, fmaf(numer, rrv, acc[r]));
            }
        }
    }

    #pragma unroll
    for (int oo = 0; oo < 16; ++oo) red[wv][lane][oo] = acc[oo];
    __syncthreads();
    #pragma unroll
    for (int e = 0; e < 4; ++e) {
        const int l = threadIdx.x & 63;
        const int r = (threadIdx.x >> 6) + e * 4;
        const float s = (red[0][l][r] + red[1][l][r]) + (red[2][l][r] + red[3][l][r]);
        const int row = (r & 3) + 8 * (r >> 2) + 4 * (l >> 5);
        out[(size_t)(b0 + row) * OUT_F + ot * 32 + (l & 31)] = s;
    }
}

// ======================= TIER 3: scalar fallback =======================

__global__ __launch_bounds__(256)
void padekan_fallback(const float* __restrict__ x,  const float* __restrict__ base_w,
                      const float* __restrict__ num_w, const float* __restrict__ den_w,
                      const float* __restrict__ hbias, const float* __restrict__ hweight,
                      const float* __restrict__ l2w, const float* __restrict__ pw,
                      const float* __restrict__ grid, float* __restrict__ out)
{
    const int b = blockIdx.x;
    const int o = threadIdx.x;
    const float g0 = grid[0];
    const float inv_h = 1.0f / (grid[1] - grid[0]);
    const float* xrow = x + (size_t)b * IN_F;
    float l2v = 0.f, prodv = 1.f;
    for (int i = 0; i < IN_F; ++i) { float xv = xrow[i]; l2v = fmaf(xv, xv, l2v); prodv *= xv; }
    float acc = 0.f;
    for (int i = 0; i < IN_F; ++i) {
        const float xv = xrow[i];
        const float t = (xv - g0) * inv_h;
        const float sf = floorf(t);
        const float u = t - sf;
        const float u2 = u * u, u3 = u2 * u, om = 1.0f - u;
        const float W[4] = {om * om * om / 6.0f,
                            fmaf(3.0f, u3, fmaf(-6.0f, u2, 4.0f)) / 6.0f,
                            fmaf(-3.0f, u3, fmaf(3.0f, u2, fmaf(3.0f, u, 1.0f))) / 6.0f,
                            u3 / 6.0f};
        const int si = (int)sf;
        const int oi = o * IN_F + i;
        float num = 0.f, den = fmaf(l2v, l2w[oi], fmaf(prodv, pw[oi], 1.0f));
        #pragma unroll
        for (int w = 0; w < 4; ++w) {
            const int j = si - 3 + w;
            if (j >= 0 && j < 8) {
                num = fmaf(W[w], num_w[(size_t)oi * 8 + j], num);
                den = fmaf(W[w], den_w[(size_t)oi * 8 + j], den);
            }
        }
        float q = fminf(fast_exp2(fminf((hbias[oi] - xv) * (50.0f * L2E), 99.0f)), 1e30f) + 1.0f;
        float tt = fast_exp2(-L2E * fabsf(den));
        float sp = fmaf(fast_log2(1.0f + tt), LN2, fmaxf(den, 0.0f));
        float rr = fast_rcp(q * (sp + 1e-4f));
        float silu_v = xv * fast_rcp(1.0f + fast_exp2(-L2E * xv));
        acc = fmaf(silu_v, base_w[oi], fmaf(fmaf(num, q, hweight[oi]), rr, acc));
    }
    out[(size_t)b * OUT_F + o] = acc;
}

extern "C" void kernel_launch(void* const* d_in, const int* in_sizes, int n_in,
                              void* d_out, int out_size, void* d_ws, size_t ws_size,
                              hipStream_t stream) {
    const float* xp  = (const float*)d_in[0];
    const float* bw  = (const float*)d_in[1];
    const float* nw  = (const float*)d_in[2];
    const float* dw  = (const float*)d_in[3];
    const float* hb  = (const float*)d_in[4];
    const float* hw  = (const float*)d_in[5];
    const float* lw  = (const float*)d_in[6];
    const float* pwt = (const float*)d_in[7];
    const float* gr  = (const float*)d_in[8];
    float* outp = (float*)d_out;

    // --- tier 1 (v7) workspace ---
    const size_t sbpk_b = (size_t)IN_F * B_TOTAL * sizeof(f16x8);          // 16 MB
    const size_t ex_b   = (size_t)IN_F * B_TOTAL * sizeof(float);          // 4 MB
    const size_t si2_b  = (size_t)2 * B_TOTAL * IN_F * sizeof(_Float16);   // 4 MB
    const size_t bwp_b  = (size_t)OUT_F * IN_F * sizeof(_Float16);         // 128 KB
    const size_t bf_b   = (size_t)IN_F * 8 * 64 * sizeof(f16x8);           // 2 MB each
    const size_t mi2_b  = (size_t)IN_F * OUT_F * sizeof(float2);           // 512 KB
    const size_t st_b   = (size_t)B_TOTAL * 2 * sizeof(float);             // 32 KB
    const size_t tier1  = sbpk_b + ex_b + si2_b + bwp_b + 2 * bf_b + mi2_b + st_b; // ~28.7 MB

    // --- tier 2 (R11) workspace ---
    const size_t xT_b   = (size_t)B_TOTAL * IN_F * sizeof(float);          // 4 MB
    const size_t exsi_b = (size_t)B_TOTAL * IN_F * sizeof(float2);         // 8 MB
    const size_t misc_b = (size_t)IN_F * OUT_F * sizeof(float4);           // 1 MB
    const size_t tier2  = xT_b + exsi_b + 2 * bf_b + misc_b + st_b;        // ~17.0 MB

    dim3 block(256);

    if (ws_size >= tier1) {
        char* p = (char*)d_ws;
        f16x8*     sbpk = (f16x8*)p;      p += sbpk_b;
        float*     exA  = (float*)p;      p += ex_b;
        _Float16*  si2  = (_Float16*)p;   p += si2_b;
        _Float16*  bwp  = (_Float16*)p;   p += bwp_b;
        f16x8*     bfN  = (f16x8*)p;      p += bf_b;
        f16x8*     bfD  = (f16x8*)p;      p += bf_b;
        float2*    mi2  = (float2*)p;     p += mi2_b;
        float*     l2sp = (float*)p;
        float*     prsp = l2sp + B_TOTAL;
        prep5<<<dim3(2560), block, 0, stream>>>(
            bw, nw, dw, hb, hw, lw, pwt, xp, sbpk, exA, si2, bwp, bfN, bfD,
            mi2, l2sp, prsp, outp, out_size);
        padekan_mfma7<<<dim3(2048), block, 0, stream>>>(
            sbpk, exA, si2, bwp, bfN, bfD, mi2, l2sp, prsp, outp);
    } else if (ws_size >= tier2) {
        char* p = (char*)d_ws;
        float*  xT   = (float*)p;            p += xT_b;
        float2* exsi = (float2*)p;           p += exsi_b;
        f16x8*  bfN  = (f16x8*)p;            p += bf_b;
        f16x8*  bfD  = (f16x8*)p;            p += bf_b;
        float4* misc = (float4*)p;           p += misc_b;
        float*  l2sp = (float*)p;
        float*  prsp = l2sp + B_TOTAL;
        prep_mfma<<<dim3(768), block, 0, stream>>>(
            bw, nw, dw, hb, hw, lw, pwt, xp, xT, exsi, bfN, bfD, misc, l2sp, prsp);
        padekan_mfma<<<dim3(1024), block, 0, stream>>>(
            xT, exsi, bfN, bfD, misc, l2sp, prsp, gr, outp);
    } else {
        padekan_fallback<<<dim3(B_TOTAL), dim3(OUT_F), 0, stream>>>(
            xp, bw, nw, dw, hb, hw, lw, pwt, gr, outp);
    }
}

// Round 9
// 178.435 us; speedup vs baseline: 11.8393x; 11.8393x over previous
//
#include <hip/hip_runtime.h>

// PadeKANLayer: B=4096, IN=256, OUT=256, 8 spline terms, UNIFORM grid (h=0.4).
// R19 = exact revert to R17 (best verified: 179.8 us total, main 110 us).
// R18 post-mortem (PMC): unroll-2 double-register-set spilled to scratch
// (FETCH 4.2 GB / WRITE 3.3 GB of stack traffic, VALUBusy 4%) — by-reference
// lambda + two macro sets made pipeline registers addressable, defeating
// regalloc. Known cliffs, do not revisit: >2048 blocks (R14: L2 thrash),
// unroll-2 named sets (R18: spill). R17 structure: 1-deep prefetch pipeline,
// 2048 blocks, launch_bounds(256,4), L2E-folded den weights, b-tile XCD
// swizzle. Tier-2 fallback: R11 kernel. Tier-3: scalar fallback.

#define IN_F 256
#define OUT_F 256
#define B_TOTAL 4096
#define NWAVE 4
#define NS 4

constexpr float L2E = 1.4426950408889634f;   // log2(e)
constexpr float LN2 = 0.6931471805599453f;   // ln(2)

typedef _Float16 f16x8 __attribute__((ext_vector_type(8)));
typedef float    f32x16 __attribute__((ext_vector_type(16)));

__device__ __forceinline__ float fast_exp2(float a) { return __builtin_amdgcn_exp2f(a); }
__device__ __forceinline__ float fast_log2(float a) { return __builtin_amdgcn_logf(a); }
__device__ __forceinline__ float fast_rcp(float a)  { return __builtin_amdgcn_rcpf(a); }

// ======================= TIER 1: MFMA v6 (R17) =======================

// prep5 sections:
//  [0,1024)    x 64x16 tiles: transpose -> sbpk (f16x8), ex, siluH/L
//  [1024,1280) weight pack: bfN/bfD (den side *L2E), misc2, bwp
//  [1280,1536) row stats l2s/prs
//  [1536,2560) zero out[]
__global__ __launch_bounds__(256)
void prep5(const float* __restrict__ bw, const float* __restrict__ nw,
           const float* __restrict__ dw, const float* __restrict__ hb,
           const float* __restrict__ hw, const float* __restrict__ lw,
           const float* __restrict__ pw, const float* __restrict__ x,
           f16x8* __restrict__ sbpk, float* __restrict__ ex,
           _Float16* __restrict__ silu2,       // [2][B][IN]  (H, L)
           _Float16* __restrict__ bwp,          // [OUT][IN]
           f16x8* __restrict__ bfN, f16x8* __restrict__ bfD,
           float2* __restrict__ misc2,          // [IN][OUT]
           float* __restrict__ l2s, float* __restrict__ prs,
           float* __restrict__ out, int out_n)
{
    if (blockIdx.x < 1024) {
        // spline/ex/silu: block = 64 b x 16 i tile
        __shared__ float xs[64][17];
        __shared__ __align__(16) _Float16 sil[2][64][16];
        const int bt = blockIdx.x >> 4;   // 0..63
        const int it = blockIdx.x & 15;   // 0..15
        const int b0 = bt * 64;
        const int i0 = it * 16;
        {
            const int rr = threadIdx.x >> 2;          // 0..63 (b)
            const int c4 = (threadIdx.x & 3) * 4;     // 0,4,8,12 (i)
            const float4 v = *reinterpret_cast<const float4*>(
                x + (size_t)(b0 + rr) * IN_F + i0 + c4);
            xs[rr][c4] = v.x; xs[rr][c4 + 1] = v.y;
            xs[rr][c4 + 2] = v.z; xs[rr][c4 + 3] = v.w;
        }
        __syncthreads();
        const int bl = threadIdx.x & 63;
        const int ig = threadIdx.x >> 6;              // 0..3
        #pragma unroll
        for (int k = 0; k < 4; ++k) {
            const int il = ig * 4 + k;
            const int i = i0 + il;
            const float xv = xs[bl][il];
            // e_x (clamped so q = 1+e_hb*e_x stays finite)
            ex[(size_t)i * B_TOTAL + b0 + bl] =
                fast_exp2(fminf(-50.0f * L2E * xv, 58.0f));
            // silu hi/lo f16 split (for base MFMA)
            const float sl = xv * fast_rcp(1.0f + fast_exp2(-L2E * xv));
            const _Float16 sH = (_Float16)sl;
            sil[0][bl][il] = sH;
            sil[1][bl][il] = (_Float16)(sl - (float)sH);
            // closed-form uniform cubic B-spline; g0=-2.2, h=0.4 (build_grid)
            const float tt = (xv + 2.2f) * 2.5f;
            const float sf = floorf(tt);
            const float u  = tt - sf;
            const float u2 = u * u;
            const float u3 = u2 * u;
            const float om = 1.0f - u;
            const float W0 = om * om * om * (1.0f / 6.0f);
            const float W1 = fmaf(3.0f, u3, fmaf(-6.0f, u2, 4.0f)) * (1.0f / 6.0f);
            const float W2 = fmaf(-3.0f, u3, fmaf(3.0f, u2, fmaf(3.0f, u, 1.0f))) * (1.0f / 6.0f);
            const float W3 = u3 * (1.0f / 6.0f);
            const int  siq = (int)sf;
            f16x8 sb8;
            #pragma unroll
            for (int j = 0; j < 8; ++j) {
                float v = 0.f;
                v = (siq == j + 3) ? W0 : v;
                v = (siq == j + 2) ? W1 : v;
                v = (siq == j + 1) ? W2 : v;
                v = (siq == j    ) ? W3 : v;
                sb8[j] = (_Float16)v;
            }
            sbpk[(size_t)i * B_TOTAL + b0 + bl] = sb8;
        }
        __syncthreads();
        {
            // coalesced silu2 writeout: [2][B][IN] f16, 16B per thread
            const int hl = threadIdx.x >> 7;          // 0..1
            const int b2 = (threadIdx.x >> 1) & 63;   // 0..63
            const int ch = threadIdx.x & 1;           // 0..1
            const f16x8 v = *reinterpret_cast<const f16x8*>(&sil[hl][b2][ch * 8]);
            *reinterpret_cast<f16x8*>(
                silu2 + (size_t)hl * B_TOTAL * IN_F +
                (size_t)(b0 + b2) * IN_F + i0 + ch * 8) = v;
        }
    } else if (blockIdx.x < 1280) {
        // weight pack: block = i, thread = o. Den side pre-scaled by L2E.
        const int i = blockIdx.x - 1024;
        const int o = threadIdx.x;
        const int oi = o * IN_F + i;
        const float* n8 = nw + (size_t)oi * 8;
        const float* d8 = dw + (size_t)oi * 8;
        f16x8 vhi, vlo, vd;
        #pragma unroll
        for (int k = 0; k < 8; ++k) {
            const float nv = n8[k];
            const _Float16 h = (_Float16)nv;
            vhi[k] = h;
            vlo[k] = (_Float16)(nv - (float)h);
            vd[k]  = (_Float16)(d8[k] * L2E);
        }
        const float lwv = lw[oi] * L2E, pwv = pw[oi] * L2E;
        const _Float16 lwh = (_Float16)lwv;
        const _Float16 lwl = (_Float16)(lwv - (float)lwh);
        const _Float16 cEh = (_Float16)L2E;
        const _Float16 cEl = (_Float16)(L2E - (float)cEh);
        const _Float16 z0 = (_Float16)0.0f;
        // stats B half (k=8..15): pairs with A stat8 {l2h,l2h,l2l,prs,1,1,0,0}
        const f16x8 vs = {lwh, lwl, lwh, (_Float16)pwv, cEh, cEl, z0, z0};
        const int ot = o >> 5, ol = o & 31;
        const size_t base = ((size_t)i * 8 + ot) * 64;
        bfN[base + ol]      = vhi;   // lanes 0-31: k=0..7  (sb x wn_hi)
        bfN[base + 32 + ol] = vlo;   // lanes 32-63: k=8..15 (sb x wn_lo)
        bfD[base + ol]      = vd;    // k=0..7 (sb x wd*L2E)
        bfD[base + 32 + ol] = vs;    // k=8..13 stats weights (*L2E)
        misc2[(size_t)i * OUT_F + o] =
            make_float2(fast_exp2(hb[oi] * (50.0f * L2E)), hw[oi]);
        bwp[(size_t)o * IN_F + i] = (_Float16)bw[oi];
    } else if (blockIdx.x < 1536) {
        // row stats: 256 blocks x 4 waves, each wave reduces 4 rows
        const int blk = blockIdx.x - 1280;
        const int wv = threadIdx.x >> 6;
        const int lane = threadIdx.x & 63;
        const int row = blk * NWAVE + wv;
        #pragma unroll
        for (int rr = 0; rr < 4; ++rr) {
            const int r = row * 4 + rr;               // 0..4095
            const float* xr = x + (size_t)r * IN_F;
            float pl2 = 0.f, ppr = 1.f;
            #pragma unroll
            for (int c = 0; c < 4; ++c) {
                float xv = xr[c * 64 + lane];
                pl2 = fmaf(xv, xv, pl2);
                ppr *= xv;
            }
            #pragma unroll
            for (int m = 1; m < 64; m <<= 1) {
                pl2 += __shfl_xor(pl2, m);
                ppr *= __shfl_xor(ppr, m);
            }
            if (lane == 0) { l2s[r] = pl2; prs[r] = ppr; }
        }
    } else {
        const size_t base = ((size_t)(blockIdx.x - 1536) * 256 + threadIdx.x) * 4;
        if (base + 4 <= (size_t)out_n)
            *reinterpret_cast<float4*>(out + base) = make_float4(0.f, 0.f, 0.f, 0.f);
    }
}

// main: 2048 blocks = 8 xcd x (8 ot x 16 btl x 2 ih). Software-pipelined:
// prefetch iter ii+1's loads before iter ii's MFMA+glue (latency-bound fix).
// C layout (verified 32x32): col = lane&31 (=o), row = (r&3)+8*(r>>2)+4*(lane>>5).
__global__ __launch_bounds__(256, 4)
void padekan_mfma6(const f16x8* __restrict__ sbpk, const float* __restrict__ ex,
                   const _Float16* __restrict__ silu2, const _Float16* __restrict__ bwp,
                   const f16x8* __restrict__ bfN, const f16x8* __restrict__ bfD,
                   const float2* __restrict__ misc2, const float* __restrict__ l2s,
                   const float* __restrict__ prs, float* __restrict__ out)
{
    __shared__ float red[NS][64][17];   // 17408 B

    const int lane = threadIdx.x & 63;
    const int wv = threadIdx.x >> 6;    // i-chunk
    const int xcd = blockIdx.x & 7;     // XCD -> b-tile group
    const int r   = blockIdx.x >> 3;    // 0..255
    const int ot  = r >> 5;             // 0..7  (slow per XCD: weights swap)
    const int btl = (r >> 1) & 15;      // 0..15
    const int ih  = r & 1;              // i-half
    const int bt  = xcd * 16 + btl;     // 0..127
    const int bl = lane & 31;
    const int hi = lane >> 5;
    const int b0 = bt * 32;
    const int bme = b0 + bl;

    // stats A half (hi lanes, k=8..15): {l2hi,l2hi,l2lo,prs,1,1,0,0}
    const float l2v = l2s[bme];
    const float prv = prs[bme];
    const _Float16 l2h = (_Float16)l2v;
    const _Float16 l2l = (_Float16)(l2v - (float)l2h);
    const _Float16 z0 = (_Float16)0.0f;
    const _Float16 one = (_Float16)1.0f;
    const f16x8 stat8 = {l2h, l2h, l2l, (_Float16)prv, one, one, z0, z0};

    const f32x16 zero16 = {};
    f32x16 acc = {};

    const int i0 = ih * 128 + wv * 32;

    const f16x8*    sb_p = sbpk + (size_t)i0 * B_TOTAL + bme;
    const f16x8*    bn_p = bfN + ((size_t)i0 * 8 + ot) * 64 + lane;
    const f16x8*    bd_p = bfD + ((size_t)i0 * 8 + ot) * 64 + lane;
    const float2*   mi_p = misc2 + (size_t)i0 * OUT_F + ot * 32 + bl;
    const float*    ep   = ex + (size_t)i0 * B_TOTAL + b0 + hi * 4;
    const _Float16* si_p = silu2 + (size_t)hi * (B_TOTAL * IN_F) + (size_t)bme * IN_F + i0;
    const _Float16* bw_p = bwp + (size_t)(ot * 32 + bl) * IN_F + i0;

    // one MFMA pair + 16-element glue on current registers
    auto glue = [&](const f16x8& sbv_c, const f16x8& vbN_c, const f16x8& vbD_c,
                    const float2& mi_c, const float4& eA0, const float4& eA1,
                    const float4& eA2, const float4& eA3) {
        const f16x8 aD = hi ? stat8 : sbv_c;
        f32x16 cn = __builtin_amdgcn_mfma_f32_32x32x16_f16(sbv_c, vbN_c, zero16, 0, 0, 0);
        f32x16 cd = __builtin_amdgcn_mfma_f32_32x32x16_f16(aD, vbD_c, zero16, 0, 0, 0);
        const float4 eAs[4] = {eA0, eA1, eA2, eA3};
        #pragma unroll
        for (int gq = 0; gq < 4; ++gq) {
            const float exq[4] = {eAs[gq].x, eAs[gq].y, eAs[gq].z, eAs[gq].w};
            #pragma unroll
            for (int j = 0; j < 4; ++j) {
                const int rr_ = gq * 4 + j;
                // cd = L2E*den (pre-scaled); naive softplus exact for |den|<85
                const float t1  = fast_exp2(cd[rr_]);
                const float spe = fmaf(fast_log2(1.0f + t1), LN2, 1e-4f);
                const float q   = fmaf(exq[j], mi_c.x, 1.0f);
                const float rrv = fast_rcp(q * spe);
                acc[rr_] = fmaf(fmaf(cn[rr_], q, mi_c.y), rrv, acc[rr_]);
            }
        }
    };

    // ---- pipelined main loop: prefetch ii+1, compute ii ----
    f16x8 sbv = *sb_p, vbN = *bn_p, vbD = *bd_p;
    float2 mi = *mi_p;
    float4 e0 = *reinterpret_cast<const float4*>(ep);
    float4 e1 = *reinterpret_cast<const float4*>(ep + 8);
    float4 e2 = *reinterpret_cast<const float4*>(ep + 16);
    float4 e3 = *reinterpret_cast<const float4*>(ep + 24);

    #pragma unroll 1
    for (int ii = 0; ii < 31; ++ii) {
        if ((ii & 7) == 0) {
            // base_out MFMA: k0-7 = silu_hi x bw, k8-15 = silu_lo x bw (8 i's)
            const int seg = ii >> 3;
            const f16x8 sfr = *reinterpret_cast<const f16x8*>(si_p + seg * 8);
            const f16x8 wfr = *reinterpret_cast<const f16x8*>(bw_p + seg * 8);
            acc = __builtin_amdgcn_mfma_f32_32x32x16_f16(sfr, wfr, acc, 0, 0, 0);
        }
        sb_p += B_TOTAL; bn_p += 8 * 64; bd_p += 8 * 64; mi_p += OUT_F; ep += B_TOTAL;
        const f16x8 sbv_n = *sb_p;
        const f16x8 vbN_n = *bn_p;
        const f16x8 vbD_n = *bd_p;
        const float2 mi_n = *mi_p;
        const float4 f0 = *reinterpret_cast<const float4*>(ep);
        const float4 f1 = *reinterpret_cast<const float4*>(ep + 8);
        const float4 f2 = *reinterpret_cast<const float4*>(ep + 16);
        const float4 f3 = *reinterpret_cast<const float4*>(ep + 24);

        glue(sbv, vbN, vbD, mi, e0, e1, e2, e3);

        sbv = sbv_n; vbN = vbN_n; vbD = vbD_n; mi = mi_n;
        e0 = f0; e1 = f1; e2 = f2; e3 = f3;
    }
    // epilogue: last iteration (no prefetch beyond range)
    glue(sbv, vbN, vbD, mi, e0, e1, e2, e3);

    // cross-wave reduce (4 i-chunks), atomic combine of the 2 ih halves
    #pragma unroll
    for (int oo = 0; oo < 16; ++oo) red[wv][lane][oo] = acc[oo];
    __syncthreads();
    #pragma unroll
    for (int e = 0; e < 4; ++e) {
        const int l = threadIdx.x & 63;
        const int rr_ = (threadIdx.x >> 6) + e * 4;     // 0..15
        const float s = (red[0][l][rr_] + red[1][l][rr_]) +
                        (red[2][l][rr_] + red[3][l][rr_]);
        const int row = (rr_ & 3) + 8 * (rr_ >> 2) + 4 * (l >> 5);
        atomicAdd(&out[(size_t)(b0 + row) * OUT_F + ot * 32 + (l & 31)], s);
    }
}

// ======================= TIER 2: R11 MFMA path =======================

__global__ __launch_bounds__(256)
void prep_mfma(const float* __restrict__ bw, const float* __restrict__ nw,
               const float* __restrict__ dw, const float* __restrict__ hb,
               const float* __restrict__ hw, const float* __restrict__ lw,
               const float* __restrict__ pw, const float* __restrict__ x,
               float* __restrict__ xT, float2* __restrict__ exsi,
               f16x8* __restrict__ bfN, f16x8* __restrict__ bfD,
               float4* __restrict__ misc,
               float* __restrict__ l2s, float* __restrict__ prs)
{
    if (blockIdx.x < 256) {
        const int i = blockIdx.x;
        const int o = threadIdx.x;
        const int oi = o * IN_F + i;
        const float* n8 = nw + (size_t)oi * 8;
        const float* d8 = dw + (size_t)oi * 8;
        f16x8 vhi, vlo, vd;
        #pragma unroll
        for (int k = 0; k < 8; ++k) {
            const float nv = n8[k];
            const _Float16 h = (_Float16)nv;
            vhi[k] = h;
            vlo[k] = (_Float16)(nv - (float)h);
            vd[k]  = (_Float16)d8[k];
        }
        const float lwv = lw[oi], pwv = pw[oi];
        const _Float16 lwh = (_Float16)lwv;
        const _Float16 lwl = (_Float16)(lwv - (float)lwh);
        const _Float16 z0 = (_Float16)0.0f;
        const f16x8 vs = {lwh, lwl, lwh, (_Float16)pwv, (_Float16)1.0f, z0, z0, z0};
        const int ot = o >> 5, ol = o & 31;
        const size_t base = ((size_t)i * 8 + ot) * 64;
        bfN[base + ol]      = vhi;
        bfN[base + 32 + ol] = vlo;
        bfD[base + ol]      = vd;
        bfD[base + 32 + ol] = vs;
        misc[(size_t)i * OUT_F + o] =
            make_float4(fast_exp2(hb[oi] * (50.0f * L2E)), hw[oi], bw[oi], 0.0f);
    } else if (blockIdx.x < 512) {
        __shared__ float t[64][65];
        const int blk = blockIdx.x - 256;
        const int bt = blk >> 2;
        const int it = blk & 3;
        const int c  = threadIdx.x & 63;
        const int r0 = threadIdx.x >> 6;
        #pragma unroll
        for (int rr = 0; rr < 16; ++rr) {
            const int r = r0 * 16 + rr;
            t[r][c] = x[(size_t)(bt * 64 + r) * IN_F + it * 64 + c];
        }
        __syncthreads();
        #pragma unroll
        for (int rr = 0; rr < 16; ++rr) {
            const int r = r0 * 16 + rr;
            const float v = t[c][r];
            const size_t idx = (size_t)(it * 64 + r) * B_TOTAL + bt * 64 + c;
            xT[idx] = v;
            const float exv = fast_exp2(fminf(-50.0f * L2E * v, 58.0f));
            const float sl = v * fast_rcp(1.0f + fast_exp2(-L2E * v));
            exsi[idx] = make_float2(exv, sl);
        }
    } else {
        const int blk = blockIdx.x - 512;
        const int wv = threadIdx.x >> 6;
        const int lane = threadIdx.x & 63;
        const int row = blk * NWAVE + wv;
        #pragma unroll
        for (int rr = 0; rr < 4; ++rr) {
            const int r = row * 4 + rr;
            const float* xr = x + (size_t)r * IN_F;
            float pl2 = 0.f, ppr = 1.f;
            #pragma unroll
            for (int c = 0; c < 4; ++c) {
                float xv = xr[c * 64 + lane];
                pl2 = fmaf(xv, xv, pl2);
                ppr *= xv;
            }
            #pragma unroll
            for (int m = 1; m < 64; m <<= 1) {
                pl2 += __shfl_xor(pl2, m);
                ppr *= __shfl_xor(ppr, m);
            }
            if (lane == 0) { l2s[r] = pl2; prs[r] = ppr; }
        }
    }
}

__global__ __launch_bounds__(256, 4)
void padekan_mfma(const float* __restrict__ xT, const float2* __restrict__ exsi,
                  const f16x8* __restrict__ bfN, const f16x8* __restrict__ bfD,
                  const float4* __restrict__ misc, const float* __restrict__ l2s,
                  const float* __restrict__ prs, const float* __restrict__ grid,
                  float* __restrict__ out)
{
    __shared__ float red[NS][64][17];

    const int lane = threadIdx.x & 63;
    const int wv = threadIdx.x >> 6;
    const int ot = blockIdx.x & 7;
    const int bt = blockIdx.x >> 3;
    const int bl = lane & 31;
    const int hi = lane >> 5;
    const int b0 = bt * 32;

    const float g0 = grid[0];
    const float inv_h = 1.0f / (grid[1] - grid[0]);

    const float l2v = l2s[b0 + bl];
    const float prv = prs[b0 + bl];
    const _Float16 l2h = (_Float16)l2v;
    const _Float16 l2l = (_Float16)(l2v - (float)l2h);
    const _Float16 z0 = (_Float16)0.0f;
    const f16x8 stat8 = {l2h, l2h, l2l, (_Float16)prv, (_Float16)1.0f, z0, z0, z0};

    const f32x16 zero16 = {};
    f32x16 acc = {};

    const int i0 = wv * 64;
    #pragma unroll 1
    for (int ii = 0; ii < 64; ++ii) {
        const int i = i0 + ii;
        const float xv = xT[(size_t)i * B_TOTAL + b0 + bl];

        const float t  = (xv - g0) * inv_h;
        const float sf = floorf(t);
        const float u  = t - sf;
        const float u2 = u * u;
        const float u3 = u2 * u;
        const float om = 1.0f - u;
        const float W0 = om * om * om * (1.0f / 6.0f);
        const float W1 = fmaf(3.0f, u3, fmaf(-6.0f, u2, 4.0f)) * (1.0f / 6.0f);
        const float W2 = fmaf(-3.0f, u3, fmaf(3.0f, u2, fmaf(3.0f, u, 1.0f))) * (1.0f / 6.0f);
        const float W3 = u3 * (1.0f / 6.0f);
        const int  si = (int)sf;

        f16x8 aN;
        #pragma unroll
        for (int j = 0; j < 8; ++j) {
            float v = 0.f;
            v = (si == j + 3) ? W0 : v;
            v = (si == j + 2) ? W1 : v;
            v = (si == j + 1) ? W2 : v;
            v = (si == j    ) ? W3 : v;
            aN[j] = (_Float16)v;
        }
        const f16x8 aD = hi ? stat8 : aN;

        const size_t fb = ((size_t)i * 8 + ot) * 64 + lane;
        const f16x8 vbN = bfN[fb];
        const f16x8 vbD = bfD[fb];
        const float4 mi = misc[(size_t)i * OUT_F + ot * 32 + bl];

        f32x16 cn = __builtin_amdgcn_mfma_f32_32x32x16_f16(aN, vbN, zero16, 0, 0, 0);
        f32x16 cd = __builtin_amdgcn_mfma_f32_32x32x16_f16(aD, vbD, zero16, 0, 0, 0);

        const float2* ep = exsi + (size_t)i * B_TOTAL + b0 + hi * 4;
        #pragma unroll
        for (int gq = 0; gq < 4; ++gq) {
            const float4 eA = *reinterpret_cast<const float4*>(ep + gq * 8);
            const float4 eB = *reinterpret_cast<const float4*>(ep + gq * 8 + 2);
            const float exq[4] = {eA.x, eA.z, eB.x, eB.z};
            const float svq[4] = {eA.y, eA.w, eB.y, eB.w};
            #pragma unroll
            for (int j = 0; j < 4; ++j) {
                const int r = gq * 4 + j;
                const float den = cd[r];
                const float ttv = fast_exp2(-L2E * fabsf(den));
                const float sp  = fmaf(fast_log2(1.0f + ttv), LN2, fmaxf(den, 0.0f));
                const float q   = fmaf(exq[j], mi.x, 1.0f);
                const float rrv = fast_rcp(q * (sp + 1e-4f));
                const float numer = fmaf(cn[r], q, mi.y);
                acc[r] = fmaf(svq[j], mi.z, fmaf(numer, rrv, acc[r]));
            }
        }
    }

    #pragma unroll
    for (int oo = 0; oo < 16; ++oo) red[wv][lane][oo] = acc[oo];
    __syncthreads();
    #pragma unroll
    for (int e = 0; e < 4; ++e) {
        const int l = threadIdx.x & 63;
        const int r = (threadIdx.x >> 6) + e * 4;
        const float s = (red[0][l][r] + red[1][l][r]) + (red[2][l][r] + red[3][l][r]);
        const int row = (r & 3) + 8 * (r >> 2) + 4 * (l >> 5);
        out[(size_t)(b0 + row) * OUT_F + ot * 32 + (l & 31)] = s;
    }
}

// ======================= TIER 3: scalar fallback =======================

__global__ __launch_bounds__(256)
void padekan_fallback(const float* __restrict__ x,  const float* __restrict__ base_w,
                      const float* __restrict__ num_w, const float* __restrict__ den_w,
                      const float* __restrict__ hbias, const float* __restrict__ hweight,
                      const float* __restrict__ l2w, const float* __restrict__ pw,
                      const float* __restrict__ grid, float* __restrict__ out)
{
    const int b = blockIdx.x;
    const int o = threadIdx.x;
    const float g0 = grid[0];
    const float inv_h = 1.0f / (grid[1] - grid[0]);
    const float* xrow = x + (size_t)b * IN_F;
    float l2v = 0.f, prodv = 1.f;
    for (int i = 0; i < IN_F; ++i) { float xv = xrow[i]; l2v = fmaf(xv, xv, l2v); prodv *= xv; }
    float acc = 0.f;
    for (int i = 0; i < IN_F; ++i) {
        const float xv = xrow[i];
        const float t = (xv - g0) * inv_h;
        const float sf = floorf(t);
        const float u = t - sf;
        const float u2 = u * u, u3 = u2 * u, om = 1.0f - u;
        const float W[4] = {om * om * om / 6.0f,
                            fmaf(3.0f, u3, fmaf(-6.0f, u2, 4.0f)) / 6.0f,
                            fmaf(-3.0f, u3, fmaf(3.0f, u2, fmaf(3.0f, u, 1.0f))) / 6.0f,
                            u3 / 6.0f};
        const int si = (int)sf;
        const int oi = o * IN_F + i;
        float num = 0.f, den = fmaf(l2v, l2w[oi], fmaf(prodv, pw[oi], 1.0f));
        #pragma unroll
        for (int w = 0; w < 4; ++w) {
            const int j = si - 3 + w;
            if (j >= 0 && j < 8) {
                num = fmaf(W[w], num_w[(size_t)oi * 8 + j], num);
                den = fmaf(W[w], den_w[(size_t)oi * 8 + j], den);
            }
        }
        float q = fminf(fast_exp2(fminf((hbias[oi] - xv) * (50.0f * L2E), 99.0f)), 1e30f) + 1.0f;
        float tt = fast_exp2(-L2E * fabsf(den));
        float sp = fmaf(fast_log2(1.0f + tt), LN2, fmaxf(den, 0.0f));
        float rr = fast_rcp(q * (sp + 1e-4f));
        float silu_v = xv * fast_rcp(1.0f + fast_exp2(-L2E * xv));
        acc = fmaf(silu_v, base_w[oi], fmaf(fmaf(num, q, hweight[oi]), rr, acc));
    }
    out[(size_t)b * OUT_F + o] = acc;
}

extern "C" void kernel_launch(void* const* d_in, const int* in_sizes, int n_in,
                              void* d_out, int out_size, void* d_ws, size_t ws_size,
                              hipStream_t stream) {
    const float* xp  = (const float*)d_in[0];
    const float* bw  = (const float*)d_in[1];
    const float* nw  = (const float*)d_in[2];
    const float* dw  = (const float*)d_in[3];
    const float* hb  = (const float*)d_in[4];
    const float* hw  = (const float*)d_in[5];
    const float* lw  = (const float*)d_in[6];
    const float* pwt = (const float*)d_in[7];
    const float* gr  = (const float*)d_in[8];
    float* outp = (float*)d_out;

    // --- tier 1 workspace ---
    const size_t sbpk_b = (size_t)IN_F * B_TOTAL * sizeof(f16x8);          // 16 MB
    const size_t ex_b   = (size_t)IN_F * B_TOTAL * sizeof(float);          // 4 MB
    const size_t si2_b  = (size_t)2 * B_TOTAL * IN_F * sizeof(_Float16);   // 4 MB
    const size_t bwp_b  = (size_t)OUT_F * IN_F * sizeof(_Float16);         // 128 KB
    const size_t bf_b   = (size_t)IN_F * 8 * 64 * sizeof(f16x8);           // 2 MB each
    const size_t mi2_b  = (size_t)IN_F * OUT_F * sizeof(float2);           // 512 KB
    const size_t st_b   = (size_t)B_TOTAL * 2 * sizeof(float);             // 32 KB
    const size_t tier1  = sbpk_b + ex_b + si2_b + bwp_b + 2 * bf_b + mi2_b + st_b; // ~28.7 MB

    // --- tier 2 (R11) workspace ---
    const size_t xT_b   = (size_t)B_TOTAL * IN_F * sizeof(float);          // 4 MB
    const size_t exsi_b = (size_t)B_TOTAL * IN_F * sizeof(float2);         // 8 MB
    const size_t misc_b = (size_t)IN_F * OUT_F * sizeof(float4);           // 1 MB
    const size_t tier2  = xT_b + exsi_b + 2 * bf_b + misc_b + st_b;        // ~17.0 MB

    dim3 block(256);

    if (ws_size >= tier1) {
        char* p = (char*)d_ws;
        f16x8*     sbpk = (f16x8*)p;      p += sbpk_b;
        float*     exA  = (float*)p;      p += ex_b;
        _Float16*  si2  = (_Float16*)p;   p += si2_b;
        _Float16*  bwp  = (_Float16*)p;   p += bwp_b;
        f16x8*     bfN  = (f16x8*)p;      p += bf_b;
        f16x8*     bfD  = (f16x8*)p;      p += bf_b;
        float2*    mi2  = (float2*)p;     p += mi2_b;
        float*     l2sp = (float*)p;
        float*     prsp = l2sp + B_TOTAL;
        prep5<<<dim3(2560), block, 0, stream>>>(
            bw, nw, dw, hb, hw, lw, pwt, xp, sbpk, exA, si2, bwp, bfN, bfD,
            mi2, l2sp, prsp, outp, out_size);
        padekan_mfma6<<<dim3(2048), block, 0, stream>>>(
            sbpk, exA, si2, bwp, bfN, bfD, mi2, l2sp, prsp, outp);
    } else if (ws_size >= tier2) {
        char* p = (char*)d_ws;
        float*  xT   = (float*)p;            p += xT_b;
        float2* exsi = (float2*)p;           p += exsi_b;
        f16x8*  bfN  = (f16x8*)p;            p += bf_b;
        f16x8*  bfD  = (f16x8*)p;            p += bf_b;
        float4* misc = (float4*)p;           p += misc_b;
        float*  l2sp = (float*)p;
        float*  prsp = l2sp + B_TOTAL;
        prep_mfma<<<dim3(768), block, 0, stream>>>(
            bw, nw, dw, hb, hw, lw, pwt, xp, xT, exsi, bfN, bfD, misc, l2sp, prsp);
        padekan_mfma<<<dim3(1024), block, 0, stream>>>(
            xT, exsi, bfN, bfD, misc, l2sp, prsp, gr, outp);
    } else {
        padekan_fallback<<<dim3(B_TOTAL), dim3(OUT_F), 0, stream>>>(
            xp, bw, nw, dw, hb, hw, lw, pwt, gr, outp);
    }
}